// Round 4
// baseline (511.708 us; speedup 1.0000x reference)
//
#include <hip/hip_runtime.h>
#include <stdint.h>

#define HB 16
#define HC 80
#define HH 256
#define HWD 256
#define PLANE (HH * HWD)        // 65536
#define NPLANES (HB * HC)       // 1280
#define K_TOP 100
#define CAP 2048                // per-plane candidate buffer
#define OUTCAP 256
#define NEG_INF (-3.402823466e38f)

__device__ __forceinline__ int blockReduceSum(int v, int* sred) {
    for (int off = 32; off > 0; off >>= 1) v += __shfl_down(v, off);
    int t = threadIdx.x;
    __syncthreads();                    // protect sred reuse across calls
    if ((t & 63) == 0) sred[t >> 6] = v;
    __syncthreads();
    return sred[0] + sred[1] + sred[2] + sred[3];
}

__device__ __forceinline__ bool better(float a, int ai, float b, int bi) {
    return (a > b) || (a == b && ai < bi);
}

// descending sort of 256 (val,idx) pairs, ties -> smaller idx first
__device__ void bitonic256(float* sv, int* si) {
    int t = threadIdx.x;
    for (unsigned k = 2; k <= 256; k <<= 1) {
        for (unsigned j = k >> 1; j > 0; j >>= 1) {
            __syncthreads();
            unsigned i = (unsigned)t, x = i ^ j;
            if (x > i) {
                float a = sv[i], bv = sv[x];
                int ai = si[i], bi = si[x];
                bool sw = ((i & k) == 0) ? better(bv, bi, a, ai) : better(a, ai, bv, bi);
                if (sw) { sv[i] = bv; si[i] = bi; sv[x] = a; si[x] = ai; }
            }
        }
    }
    __syncthreads();
}

// unconditional in-plane row load (r is wave-uniform scalar)
__device__ __forceinline__ float4 loadrow_u(const float* __restrict__ pl, int r, int lane) {
    return ((const float4*)(pl + r * HWD))[lane];
}

// guarded: r may be == HH (last wave's last halo row). min keeps the load
// unconditional (stays in the pipeline); -inf fix is wave-uniform.
__device__ __forceinline__ float4 loadrow_g(const float* __restrict__ pl, int r, int lane) {
    int rc = min(r, HH - 1);
    float4 v = ((const float4*)(pl + rc * HWD))[lane];
    if (r >= HH) { v.x = NEG_INF; v.y = NEG_INF; v.z = NEG_INF; v.w = NEG_INF; }
    return v;
}

// horizontal 3-max for 4 consecutive cols; neighbors via wave shuffle
__device__ __forceinline__ float4 hmax4(float4 v, int lane) {
    float vl = __shfl_up(v.w, 1);
    float vr = __shfl_down(v.x, 1);
    if (lane == 0) vl = NEG_INF;
    if (lane == 63) vr = NEG_INF;
    float4 h;
    h.x = fmaxf(fmaxf(vl, v.x), v.y);
    h.y = fmaxf(fmaxf(v.x, v.y), v.z);
    h.z = fmaxf(fmaxf(v.y, v.z), v.w);
    h.w = fmaxf(fmaxf(v.z, v.w), vr);
    return h;
}

// One block per (b,c) plane. Wave w streams rows [64w, 64w+63], rolling
// vertical window in registers, next-batch loads prefetched ahead of compute.
// Output: plane top-100 SORTED descending (val desc, idx asc) -> ws.
__global__ __launch_bounds__(256) void k_plane_topk(const float* __restrict__ heat,
                                                    float* __restrict__ wsv,
                                                    int* __restrict__ wsi) {
    int plane = blockIdx.x;             // b*HC + c
    int c = plane % HC;
    const float* pl = heat + (size_t)plane * PLANE;
    int t = threadIdx.x;
    int lane = t & 63;
    int rs = __builtin_amdgcn_readfirstlane((t >> 6) << 6);   // scalar row base

    __shared__ float bufv[CAP];
    __shared__ int   bufi[CAP];
    __shared__ float outv[OUTCAP];
    __shared__ int   outi[OUTCAP];
    __shared__ int   cnt, cnt2;
    __shared__ int   sred[4];

    float thr = 0.98f;
    int n = 0;
    for (int attempt = 0; attempt < 3; ++attempt) {
        if (t == 0) cnt = 0;
        __syncthreads();

        // prolog: rows rs-1, rs, and prefetch rows rs+1..rs+4 (all < HH)
        float4 rm1 = loadrow_u(pl, max(rs - 1, 0), lane);
        float4 r0  = loadrow_u(pl, rs, lane);
        float4 n0 = loadrow_u(pl, rs + 1, lane);
        float4 n1 = loadrow_u(pl, rs + 2, lane);
        float4 n2 = loadrow_u(pl, rs + 3, lane);
        float4 n3 = loadrow_u(pl, rs + 4, lane);
        if (rs == 0) { rm1.x = NEG_INF; rm1.y = NEG_INF; rm1.z = NEG_INF; rm1.w = NEG_INF; }
        float4 hA = hmax4(rm1, lane);
        float4 hB = hmax4(r0, lane);
        float4 vB = r0;

        for (int j = 0; j < 16; ++j) {
            float4 c0 = n0, c1 = n1, c2 = n2, c3 = n3;
            if (j < 15) {               // prefetch next batch BEFORE consuming cur
                int rb = rs + 4 * j + 5;
                n0 = loadrow_u(pl, rb, lane);
                n1 = loadrow_u(pl, rb + 1, lane);
                n2 = loadrow_u(pl, rb + 2, lane);
                n3 = loadrow_g(pl, rb + 3, lane);   // row rs+4j+8 can be HH
            }
#pragma unroll
            for (int u = 0; u < 4; ++u) {
                float4 nr = (u == 0) ? c0 : (u == 1) ? c1 : (u == 2) ? c2 : c3;
                int row = rs + 4 * j + u;
                float4 hC = hmax4(nr, lane);
                float p0 = fmaxf(fmaxf(hA.x, hB.x), hC.x);
                float p1 = fmaxf(fmaxf(hA.y, hB.y), hC.y);
                float p2 = fmaxf(fmaxf(hA.z, hB.z), hC.z);
                float p3 = fmaxf(fmaxf(hA.w, hB.w), hC.w);
                bool k0 = (vB.x >= p0) && (vB.x > thr);
                bool k1 = (vB.y >= p1) && (vB.y > thr);
                bool k2 = (vB.z >= p2) && (vB.z > thr);
                bool k3 = (vB.w >= p3) && (vB.w > thr);
                if (k0 | k1 | k2 | k3) {            // single execz-skip, rare
                    int colb = lane << 2;
                    if (k0) { int p = atomicAdd(&cnt, 1);
                        if (p < CAP) { bufv[p] = vB.x; bufi[p] = (c << 16) | (row << 8) | colb; } }
                    if (k1) { int p = atomicAdd(&cnt, 1);
                        if (p < CAP) { bufv[p] = vB.y; bufi[p] = (c << 16) | (row << 8) | (colb + 1); } }
                    if (k2) { int p = atomicAdd(&cnt, 1);
                        if (p < CAP) { bufv[p] = vB.z; bufi[p] = (c << 16) | (row << 8) | (colb + 2); } }
                    if (k3) { int p = atomicAdd(&cnt, 1);
                        if (p < CAP) { bufv[p] = vB.w; bufi[p] = (c << 16) | (row << 8) | (colb + 3); } }
                }
                hA = hB; hB = hC; vB = nr;
            }
        }
        __syncthreads();
        n = cnt;
        __syncthreads();                 // everyone read cnt before any reset
        if (n >= K_TOP && n <= CAP) break;
        if (n > CAP) thr = 1.0f - (1.0f - thr) * 0.25f;   // too many: raise
        else thr = (attempt == 0) ? 0.5f : 0.01f;         // too few: lower
    }
    int nn = min(n, CAP);

    // candidates to regs for counting
    float regv[CAP / 256];
#pragma unroll
    for (int k = 0; k < CAP / 256; ++k) {
        int s = t + (k << 8);
        regv[k] = (s < nn) ? bufv[s] : NEG_INF;
    }

    // bit-space binary search for the 100th-largest value.
    // invariant: count(>= float(lo)) >= 100 (candidates all > thr),
    //            count(>= float(hi)) == 0  (uniform data < 1.0)
    float T100;
    if (nn >= K_TOP) {
        unsigned lo = __float_as_uint(thr), hi = 0x3F800001u;
        while (hi - lo > 1u) {
            unsigned mid = (lo + hi) >> 1u;
            float mv = __uint_as_float(mid);
            int cl = 0;
#pragma unroll
            for (int k = 0; k < CAP / 256; ++k) cl += (regv[k] >= mv) ? 1 : 0;
            int tot = blockReduceSum(cl, sred);
            if (tot >= K_TOP) lo = mid; else hi = mid;
        }
        T100 = __uint_as_float(lo);
    } else {
        T100 = NEG_INF;
    }

    // collect all >= T100 (typically exactly 100)
    outv[t] = NEG_INF; outi[t] = 0x7fffffff;
    if (t == 0) cnt2 = 0;
    __syncthreads();
#pragma unroll
    for (int k = 0; k < CAP / 256; ++k) {
        int s = t + (k << 8);
        if (s < nn && bufv[s] >= T100) {
            int p = atomicAdd(&cnt2, 1);
            if (p < OUTCAP) { outv[p] = bufv[s]; outi[p] = bufi[s]; }
        }
    }
    __syncthreads();
    // ALWAYS sort: k_batch's binary-search seed reads slot 99 as the plane's
    // true 100th-largest. (R3 bug: unsorted list made slot 99 arbitrary ->
    // seed could exceed batch T100 -> selection collapsed.)
    bitonic256(outv, outi);
    if (t < K_TOP) {
        wsv[plane * K_TOP + t] = outv[t];
        wsi[plane * K_TOP + t] = outi[t];
    }
}

// One block per batch: exact top-100 of 80*100 candidates + epilogue
__global__ __launch_bounds__(256) void k_batch_out(const float* __restrict__ wsv,
                                                   const int* __restrict__ wsi,
                                                   const float* __restrict__ offset,
                                                   const float* __restrict__ wh,
                                                   float* __restrict__ out) {
    int b = blockIdx.x;
    int t = threadIdx.x;
    const int NCAND = HC * K_TOP;       // 8000
    const float* v_in = wsv + b * NCAND;
    const int*   i_in = wsi + b * NCAND;

    __shared__ float outv[OUTCAP];
    __shared__ int   outi[OUTCAP];
    __shared__ int   cnt2;
    __shared__ int   sred[4];
    __shared__ float smaxw[4];

    float regv[32];
#pragma unroll
    for (int k = 0; k < 32; ++k) {
        int s = t + (k << 8);
        regv[k] = (s < NCAND) ? v_in[s] : NEG_INF;
    }
    int cl0 = 0;
#pragma unroll
    for (int k = 0; k < 32; ++k) cl0 += (regv[k] > NEG_INF) ? 1 : 0;
    int nreal = blockReduceSum(cl0, sred);

    // seed lo: plane lists are sorted desc, so v_in[p*100+99] is plane p's
    // 100th-largest; batch T100 >= max_p of that (plane p* alone has 100
    // values >= it). Valid binary-search lower bound.
    float m = NEG_INF;
    if (t < HC) m = v_in[t * K_TOP + K_TOP - 1];
    for (int off = 32; off > 0; off >>= 1) m = fmaxf(m, __shfl_down(m, off));
    if ((t & 63) == 0) smaxw[t >> 6] = m;
    __syncthreads();
    float smax = fmaxf(fmaxf(smaxw[0], smaxw[1]), fmaxf(smaxw[2], smaxw[3]));

    float T100;
    if (nreal >= K_TOP) {
        unsigned lo = (smax > 0.0f) ? __float_as_uint(smax) : 0u;
        unsigned hi = 0x3F800001u;
        while (hi - lo > 1u) {
            unsigned mid = (lo + hi) >> 1u;
            float mv = __uint_as_float(mid);
            int cl = 0;
#pragma unroll
            for (int k = 0; k < 32; ++k) cl += (regv[k] >= mv) ? 1 : 0;
            int tot = blockReduceSum(cl, sred);
            if (tot >= K_TOP) lo = mid; else hi = mid;
        }
        T100 = __uint_as_float(lo);
    } else {
        T100 = NEG_INF;
    }

    outv[t] = NEG_INF; outi[t] = 0x7fffffff;
    if (t == 0) cnt2 = 0;
    __syncthreads();
#pragma unroll
    for (int k = 0; k < 32; ++k) {
        int s = t + (k << 8);
        if (s < NCAND && regv[k] >= T100 && regv[k] > NEG_INF) {
            int p = atomicAdd(&cnt2, 1);
            if (p < OUTCAP) { outv[p] = regv[k]; outi[p] = i_in[s]; }
        }
    }
    __syncthreads();
    bitonic256(outv, outi);             // descending output order

    if (t < K_TOP) {
        float val = outv[t];
        int idx = outi[t];
        bool valid = val > 0.01f;       // EXCEPT_THRESH, strict
        int cch = idx >> 16;
        int spatial = idx & 0xFFFF;
        int y = spatial >> 8, x = spatial & 0xFF;
        const float* offb = offset + (size_t)b * 2 * PLANE;
        const float* whb  = wh     + (size_t)b * 2 * PLANE;
        float o0 = offb[spatial], o1 = offb[PLANE + spatial];
        float w0 = whb[spatial],  w1 = whb[PLANE + spatial];
        float cx = (float)x + o0, cy = (float)y + o1;
        float hw = w0 * 0.5f, hh = w1 * 0.5f;
        int g = b * K_TOP + t;
        out[g]                = valid ? (float)cch : -1.0f;
        out[HB * K_TOP + g]   = valid ? val        : -1.0f;
        float b0 = valid ? (cx - hw) : -1.0f;     // mask BEFORE *SCALE (masked -> -4)
        float b1 = valid ? (cy - hh) : -1.0f;
        float b2 = valid ? (cx + hw) : -1.0f;
        float b3 = valid ? (cy + hh) : -1.0f;
        float* bb = out + 2 * HB * K_TOP + 4 * g;
        bb[0] = b0 * 4.0f; bb[1] = b1 * 4.0f; bb[2] = b2 * 4.0f; bb[3] = b3 * 4.0f;
    }
}

extern "C" void kernel_launch(void* const* d_in, const int* in_sizes, int n_in,
                              void* d_out, int out_size, void* d_ws, size_t ws_size,
                              hipStream_t stream) {
    (void)in_sizes; (void)n_in; (void)out_size; (void)ws_size;
    const float* heat   = (const float*)d_in[0];
    const float* offset = (const float*)d_in[1];
    const float* wh     = (const float*)d_in[2];
    float* out = (float*)d_out;
    float* wsv = (float*)d_ws;                                   // 128000 floats
    int*   wsi = (int*)((char*)d_ws + (size_t)NPLANES * K_TOP * sizeof(float));

    k_plane_topk<<<NPLANES, 256, 0, stream>>>(heat, wsv, wsi);
    k_batch_out<<<HB, 256, 0, stream>>>(wsv, wsi, offset, wh, out);
}